// Round 8
// baseline (65.729 us; speedup 1.0000x reference)
//
#include <hip/hip_runtime.h>

#define NB 32
#define NC 256
#define HW 4096
#define AFWD 0.999f
#define EPS 1e-5f

typedef float f32x4 __attribute__((ext_vector_type(4)));

// ---------------- K1: per-(b,c) stats, high occupancy ----------------
// 8192 blocks x 256 threads: many small blocks/CU -> deep VMEM queue,
// near-peak HBM read (proven in round 2).
__global__ __launch_bounds__(256) void cn_stats(const float* __restrict__ x,
                                                float* __restrict__ mu,
                                                float* __restrict__ v) {
    const int bc = blockIdx.x;
    const f32x4* xp = (const f32x4*)(x + (size_t)bc * HW);
    const int t = threadIdx.x;
    float s = 0.f, ss = 0.f;
#pragma unroll
    for (int i = 0; i < 4; ++i) {
        f32x4 val = xp[t + i * 256];
        s  += val.x + val.y + val.z + val.w;
        ss += val.x * val.x + val.y * val.y + val.z * val.z + val.w * val.w;
    }
#pragma unroll
    for (int off = 32; off > 0; off >>= 1) {
        s  += __shfl_down(s, off, 64);
        ss += __shfl_down(ss, off, 64);
    }
    __shared__ float sbuf[4], ssbuf[4];
    const int wave = t >> 6, lane = t & 63;
    if (lane == 0) { sbuf[wave] = s; ssbuf[wave] = ss; }
    __syncthreads();
    if (t == 0) {
        float S  = sbuf[0] + sbuf[1] + sbuf[2] + sbuf[3];
        float SS = ssbuf[0] + ssbuf[1] + ssbuf[2] + ssbuf[3];
        float mean = S * (1.f / HW);
        mu[bc] = mean;
        v[bc]  = SS * (1.f / HW) - mean * mean;   // E[x^2]-mu^2
    }
}

// ---------------- K2: per-channel EMA + normalize ----------------
// One block per channel (256 x 1024). EMA is block-local (no grid sync);
// normalize rereads x L3-warm (lat ~250cyc -> 16 waves suffice) + NT store.
__global__ __launch_bounds__(1024) void cn_ema_norm(
    const float* __restrict__ x,
    const float* __restrict__ mu,
    const float* __restrict__ v,
    const float* __restrict__ m,
    const float* __restrict__ var,
    const float* __restrict__ m_p,
    const float* __restrict__ var_p,
    float* __restrict__ out)
{
    const int c = blockIdx.x;          // channel
    const int t = threadIdx.x;
    const int w = t >> 6;              // wave 0..15
    const int l = t & 63;

    __shared__ float s_must[NB], s_rs[NB];
    __shared__ float e_seq[2 * NB - 1], e_seq2[2 * NB - 1];
    __shared__ float e_mu[NB], e_v[NB], e_m[NB], e_var[NB];
    __shared__ float e_munew[NB], e_varnew[NB];
    __shared__ float e_powv[NB];
    __shared__ float e_mB;

    // ---- EMA chain (threads 0..NB-1 do the work; ~1 us) ----
    if (t < NB - 1) {
        e_seq[t]  = m_p[(t + 1) * NC + c];
        e_seq2[t] = var_p[(t + 1) * NC + c];
    }
    if (t < NB) {
        float muv = mu[t * NC + c];
        e_mu[t] = muv;
        e_seq[NB - 1 + t] = muv;
        e_m[t]   = m[t * NC + c];
        e_v[t]   = v[t * NC + c];
        e_var[t] = var[t * NC + c];
    }
    if (t == 0) {
        float p = 1.f;
        for (int j = NB - 1; j >= 0; --j) { e_powv[j] = p; p *= AFWD; }
        e_mB = p;                              // AFWD^NB
    }
    __syncthreads();

    if (t < NB) {
        float tmp = 0.f;
#pragma unroll
        for (int j = 0; j < NB; ++j) tmp += e_powv[j] * e_seq[t + j];
        e_munew[t] = e_mB * e_m[t] + (1.f - AFWD) * tmp;
    }
    __syncthreads();

    if (t < NB) {
        float mst = t ? e_munew[t - 1] : e_m[NB - 1];
        s_must[t] = mst;
        float d = e_mu[t] - mst;
        e_seq2[NB - 1 + t] = e_v[t] + AFWD * d * d;
    }
    __syncthreads();

    if (t < NB) {
        float tmp = 0.f;
#pragma unroll
        for (int j = 0; j < NB; ++j) tmp += e_powv[j] * e_seq2[t + j];
        e_varnew[t] = e_mB * e_var[t] + (1.f - AFWD) * tmp;
    }
    __syncthreads();

    if (t < NB) {
        float vs = t ? e_varnew[t - 1] : e_var[NB - 1];
        s_rs[t] = 1.f / sqrtf(vs + EPS);
    }
    __syncthreads();

    // ---- normalize: wave w owns batch planes 2w, 2w+1 of channel c ----
    const int bA = 2 * w, bB = 2 * w + 1;
    const float muA = s_must[bA], rsA = s_rs[bA];
    const float muB = s_must[bB], rsB = s_rs[bB];
    const f32x4* xA = (const f32x4*)(x + ((size_t)bA * NC + c) * HW);
    const f32x4* xB = (const f32x4*)(x + ((size_t)bB * NC + c) * HW);
    f32x4* oA = (f32x4*)(out + ((size_t)bA * NC + c) * HW);
    f32x4* oB = (f32x4*)(out + ((size_t)bB * NC + c) * HW);

#pragma unroll
    for (int i = 0; i < 16; ++i) {
        f32x4 a = xA[i * 64 + l];
        __builtin_nontemporal_store((a - muA) * rsA, &oA[i * 64 + l]);
        f32x4 b = xB[i * 64 + l];
        __builtin_nontemporal_store((b - muB) * rsB, &oB[i * 64 + l]);
    }
}

extern "C" void kernel_launch(void* const* d_in, const int* in_sizes, int n_in,
                              void* d_out, int out_size, void* d_ws, size_t ws_size,
                              hipStream_t stream) {
    const float* x     = (const float*)d_in[0];
    const float* m     = (const float*)d_in[1];
    const float* var   = (const float*)d_in[2];
    const float* m_p   = (const float*)d_in[3];
    const float* var_p = (const float*)d_in[4];
    float* out = (float*)d_out;

    float* ws = (float*)d_ws;
    float* mu = ws;                 // [NB*NC]
    float* v  = ws + NB * NC;       // [NB*NC]

    cn_stats<<<NB * NC, 256, 0, stream>>>(x, mu, v);
    cn_ema_norm<<<NC, 1024, 0, stream>>>(x, mu, v, m, var, m_p, var_p, out);
}

// Round 9
// 58.178 us; speedup vs baseline: 1.1298x; 1.1298x over previous
//
#include <hip/hip_runtime.h>

#define NB 32
#define NC 256
#define HW 4096
#define AFWD 0.999f
#define EPS 1e-5f

#define LDSPL 9                      // planes cached in LDS per block (waves 0..8)
#define DYN_LDS (LDSPL * 1024 * 16)  // 147456 B

typedef float f32x4 __attribute__((ext_vector_type(4)));

// One block per channel (256 x 1024 = 16 waves). Wave w owns batch planes
// 2w, 2w+1. EMA chain is channel-local -> block-local, no grid sync.
// Waves 0..8 cache plane A in 144 KB dynamic LDS during pass 1; pass 2
// serves those from LDS (cuts the L3-latency-bound reread by 9/32).
__global__ __launch_bounds__(1024) void cn_channel(
    const float* __restrict__ x,
    const float* __restrict__ m,
    const float* __restrict__ var,
    const float* __restrict__ m_p,
    const float* __restrict__ var_p,
    float* __restrict__ out)
{
    extern __shared__ f32x4 ldsx[];    // [LDSPL * 1024]

    const int c = blockIdx.x;          // channel 0..255
    const int t = threadIdx.x;         // 0..1023
    const int w = t >> 6;              // wave 0..15
    const int l = t & 63;

    __shared__ float s_must[NB], s_rs[NB];
    __shared__ float e_seq[2 * NB - 1], e_seq2[2 * NB - 1];
    __shared__ float e_mu[NB], e_v[NB], e_m[NB], e_var[NB];
    __shared__ float e_munew[NB], e_varnew[NB];
    __shared__ float e_powv[NB];
    __shared__ float e_mB;

    const int bA = 2 * w, bB = 2 * w + 1;
    const f32x4* xA = (const f32x4*)(x + ((size_t)bA * NC + c) * HW);
    const f32x4* xB = (const f32x4*)(x + ((size_t)bB * NC + c) * HW);

    // ---------- Pass 1: streaming stats; waves 0..8 stash plane A in LDS ----------
    float sA = 0.f, ssA = 0.f, sB = 0.f, ssB = 0.f;
    if (w < LDSPL) {
#pragma unroll
        for (int i = 0; i < 16; ++i) {
            f32x4 a = xA[i * 64 + l];
            ldsx[w * 1024 + i * 64 + l] = a;
            sA  += a.x + a.y + a.z + a.w;
            ssA += a.x * a.x + a.y * a.y + a.z * a.z + a.w * a.w;
            f32x4 b = xB[i * 64 + l];
            sB  += b.x + b.y + b.z + b.w;
            ssB += b.x * b.x + b.y * b.y + b.z * b.z + b.w * b.w;
        }
    } else {
#pragma unroll
        for (int i = 0; i < 16; ++i) {
            f32x4 a = xA[i * 64 + l];
            sA  += a.x + a.y + a.z + a.w;
            ssA += a.x * a.x + a.y * a.y + a.z * a.z + a.w * a.w;
            f32x4 b = xB[i * 64 + l];
            sB  += b.x + b.y + b.z + b.w;
            ssB += b.x * b.x + b.y * b.y + b.z * b.z + b.w * b.w;
        }
    }
#pragma unroll
    for (int off = 32; off > 0; off >>= 1) {
        sA  += __shfl_down(sA, off, 64);
        ssA += __shfl_down(ssA, off, 64);
        sB  += __shfl_down(sB, off, 64);
        ssB += __shfl_down(ssB, off, 64);
    }
    __shared__ float s_mu_tmp[NB], s_v_tmp[NB];
    if (l == 0) {
        float mA = sA * (1.f / HW);
        s_mu_tmp[bA] = mA;
        s_v_tmp[bA]  = ssA * (1.f / HW) - mA * mA;
        float mBv = sB * (1.f / HW);
        s_mu_tmp[bB] = mBv;
        s_v_tmp[bB]  = ssB * (1.f / HW) - mBv * mBv;
    }
    __syncthreads();

    // ---------- In-block EMA chain ----------
    if (t < NB - 1) {
        e_seq[t]  = m_p[(t + 1) * NC + c];
        e_seq2[t] = var_p[(t + 1) * NC + c];
    }
    if (t < NB) {
        e_mu[t] = s_mu_tmp[t];
        e_v[t]  = s_v_tmp[t];
        e_seq[NB - 1 + t] = s_mu_tmp[t];
        e_m[t]   = m[t * NC + c];
        e_var[t] = var[t * NC + c];
    }
    if (t == 0) {
        float p = 1.f;
        for (int j = NB - 1; j >= 0; --j) { e_powv[j] = p; p *= AFWD; }
        e_mB = p;                              // AFWD^NB
    }
    __syncthreads();

    if (t < NB) {
        float tmp = 0.f;
#pragma unroll
        for (int j = 0; j < NB; ++j) tmp += e_powv[j] * e_seq[t + j];
        e_munew[t] = e_mB * e_m[t] + (1.f - AFWD) * tmp;
    }
    __syncthreads();

    if (t < NB) {
        float mst = t ? e_munew[t - 1] : e_m[NB - 1];
        s_must[t] = mst;
        float d = e_mu[t] - mst;
        e_seq2[NB - 1 + t] = e_v[t] + AFWD * d * d;
    }
    __syncthreads();

    if (t < NB) {
        float tmp = 0.f;
#pragma unroll
        for (int j = 0; j < NB; ++j) tmp += e_powv[j] * e_seq2[t + j];
        e_varnew[t] = e_mB * e_var[t] + (1.f - AFWD) * tmp;
    }
    __syncthreads();

    if (t < NB) {
        float vs = t ? e_varnew[t - 1] : e_var[NB - 1];
        s_rs[t] = 1.f / sqrtf(vs + EPS);
    }
    __syncthreads();

    // ---------- Pass 2: normalize (LDS for cached planes), NT store ----------
    const float muA = s_must[bA], rsA = s_rs[bA];
    const float muB = s_must[bB], rsB = s_rs[bB];
    f32x4* oA = (f32x4*)(out + ((size_t)bA * NC + c) * HW);
    f32x4* oB = (f32x4*)(out + ((size_t)bB * NC + c) * HW);

    if (w < LDSPL) {
#pragma unroll
        for (int i = 0; i < 16; ++i) {
            f32x4 a = ldsx[w * 1024 + i * 64 + l];
            __builtin_nontemporal_store((a - muA) * rsA, &oA[i * 64 + l]);
            f32x4 b = xB[i * 64 + l];            // L3-warm
            __builtin_nontemporal_store((b - muB) * rsB, &oB[i * 64 + l]);
        }
    } else {
#pragma unroll
        for (int i = 0; i < 16; ++i) {
            f32x4 a = xA[i * 64 + l];            // L3-warm
            __builtin_nontemporal_store((a - muA) * rsA, &oA[i * 64 + l]);
            f32x4 b = xB[i * 64 + l];
            __builtin_nontemporal_store((b - muB) * rsB, &oB[i * 64 + l]);
        }
    }
}

extern "C" void kernel_launch(void* const* d_in, const int* in_sizes, int n_in,
                              void* d_out, int out_size, void* d_ws, size_t ws_size,
                              hipStream_t stream) {
    const float* x     = (const float*)d_in[0];
    const float* m     = (const float*)d_in[1];
    const float* var   = (const float*)d_in[2];
    const float* m_p   = (const float*)d_in[3];
    const float* var_p = (const float*)d_in[4];
    float* out = (float*)d_out;

    // Raise dynamic-LDS cap (idempotent; not a stream op -> capture-safe).
    hipFuncSetAttribute((const void*)cn_channel,
                        hipFuncAttributeMaxDynamicSharedMemorySize, DYN_LDS);

    cn_channel<<<NC, 1024, DYN_LDS, stream>>>(x, m, var, m_p, var_p, out);
}

// Round 10
// 45.730 us; speedup vs baseline: 1.4373x; 1.2722x over previous
//
#include <hip/hip_runtime.h>

#define NB 32
#define NC 256
#define HW 4096
#define AFWD 0.999f
#define EPS 1e-5f
#define CH 4                 // planes per chunk
#define NCHUNK (NB / CH)     // 8 chunks

typedef float f32x4 __attribute__((ext_vector_type(4)));

// Incremental windowed-EMA scan for one chunk (wave 0 only, all 64 lanes).
// Key fact: mu_stale[i] = mu_new[i-1] depends only on stats of batches < i,
// so after chunk k's stats are in, every normalize param for chunk k is
// computable. seq/seq2 are appended progressively; run_munew/run_varnew
// carry the scan state in registers across chunks.
__device__ __forceinline__ void ema_chunk(
    int k, int l,
    float& run_munew, float& run_varnew,
    float* seq, float* seq2,
    const float* e_m, const float* e_var, const float* e_powv,
    float (*sp)[4][2], float* s_must, float* s_rs)
{
    const float one_m = 1.f - AFWD;
    const float pw    = e_powv[l & 31];    // AFWD^(31-j)
    const float mB32  = e_powv[NB];        // AFWD^32
#pragma unroll
    for (int ii = 0; ii < CH; ++ii) {
        const int i = k * CH + ii;
        // finalize this plane's stats from the 4 per-quarter partials
        float S  = sp[ii][0][0] + sp[ii][1][0] + sp[ii][2][0] + sp[ii][3][0];
        float SS = sp[ii][0][1] + sp[ii][1][1] + sp[ii][2][1] + sp[ii][3][1];
        float mu_i = S * (1.f / HW);
        float v_i  = SS * (1.f / HW) - mu_i * mu_i;
        if (l == 0) seq[NB - 1 + i] = mu_i;
        // mu window dot: lanes 0..31 cover j=0..31 (lanes 32..63 mirror)
        float dot = pw * seq[i + (l & 31)];
#pragma unroll
        for (int o = 1; o < 32; o <<= 1) dot += __shfl_xor(dot, o, 64);
        float munew = mB32 * e_m[i] + one_m * dot;
        float must  = i ? run_munew : e_m[NB - 1];
        float d  = mu_i - must;
        float vc = v_i + AFWD * d * d;
        if (l == 0) seq2[NB - 1 + i] = vc;
        // var window dot
        float dot2 = pw * seq2[i + (l & 31)];
#pragma unroll
        for (int o = 1; o < 32; o <<= 1) dot2 += __shfl_xor(dot2, o, 64);
        float varnew = mB32 * e_var[i] + one_m * dot2;
        float varst  = i ? run_varnew : e_var[NB - 1];
        run_munew  = munew;
        run_varnew = varnew;
        if (l == 0) {
            s_must[i] = must;
            s_rs[i]   = 1.f / sqrtf(varst + EPS);
        }
    }
}

// One block per channel, 1024 threads = 16 waves. Chunk = 4 planes;
// 4 waves per plane (quarters). Single read of x: chunk data stays in
// registers across the two syncthreads between its stats and its store,
// while the next chunk's loads are already in flight.
__global__ __launch_bounds__(1024) void cn_pipe(
    const float* __restrict__ x,
    const float* __restrict__ m,
    const float* __restrict__ var,
    const float* __restrict__ m_p,
    const float* __restrict__ var_p,
    float* __restrict__ out)
{
    const int c = blockIdx.x;          // channel
    const int t = threadIdx.x;
    const int w = t >> 6, l = t & 63;
    const int p = w >> 2;              // plane-in-chunk 0..3
    const int q = w & 3;               // quarter 0..3

    __shared__ float seq[2 * NB - 1], seq2[2 * NB - 1];
    __shared__ float e_m[NB], e_var[NB];
    __shared__ float e_powv[NB + 1];
    __shared__ float s_must[NB], s_rs[NB];
    __shared__ float sp[CH][4][2];     // [plane][quarter][s,ss]

    // ---- prologue: EMA state into LDS (visible after first syncthreads) ----
    if (t < NB - 1) {
        seq[t]  = m_p[(t + 1) * NC + c];
        seq2[t] = var_p[(t + 1) * NC + c];
    }
    if (t < NB) {
        e_m[t]   = m[t * NC + c];
        e_var[t] = var[t * NC + c];
    }
    if (t == 0) {
        float pw = 1.f;
        for (int j = NB - 1; j >= 0; --j) { e_powv[j] = pw; pw *= AFWD; }
        e_powv[NB] = pw;               // AFWD^32
    }

    float run_munew = 0.f, run_varnew = 0.f;
    f32x4 dA[4], dB[4];

#define LOADC(DST, K) do {                                                    \
        const int b_ = (K) * CH + p;                                          \
        const f32x4* xp_ = (const f32x4*)(x + ((size_t)b_ * NC + c) * HW);    \
        _Pragma("unroll")                                                     \
        for (int i_ = 0; i_ < 4; ++i_) DST[i_] = xp_[q * 256 + i_ * 64 + l];  \
    } while (0)

#define CHUNKB(K, CUR, NXT) do {                                              \
        if ((K) + 1 < NCHUNK) LOADC(NXT, (K) + 1);   /* prefetch next */      \
        float s_ = 0.f, ss_ = 0.f;                                            \
        _Pragma("unroll")                                                     \
        for (int i_ = 0; i_ < 4; ++i_) {                                      \
            f32x4 a_ = CUR[i_];                                               \
            s_  += a_.x + a_.y + a_.z + a_.w;                                 \
            ss_ += a_.x * a_.x + a_.y * a_.y + a_.z * a_.z + a_.w * a_.w;     \
        }                                                                     \
        _Pragma("unroll")                                                     \
        for (int o_ = 32; o_ > 0; o_ >>= 1) {                                 \
            s_  += __shfl_down(s_, o_, 64);                                   \
            ss_ += __shfl_down(ss_, o_, 64);                                  \
        }                                                                     \
        if (l == 0) { sp[p][q][0] = s_; sp[p][q][1] = ss_; }                  \
        __syncthreads();                                                      \
        if (w == 0)                                                           \
            ema_chunk((K), l, run_munew, run_varnew, seq, seq2,               \
                      e_m, e_var, e_powv, sp, s_must, s_rs);                  \
        __syncthreads();                                                      \
        {                                                                     \
            const int b_ = (K) * CH + p;                                      \
            const float mu_ = s_must[b_], rs_ = s_rs[b_];                     \
            f32x4* op_ = (f32x4*)(out + ((size_t)b_ * NC + c) * HW);          \
            _Pragma("unroll")                                                 \
            for (int i_ = 0; i_ < 4; ++i_)                                    \
                __builtin_nontemporal_store((CUR[i_] - mu_) * rs_,            \
                                            &op_[q * 256 + i_ * 64 + l]);     \
        }                                                                     \
    } while (0)

    LOADC(dA, 0);
    CHUNKB(0, dA, dB);
    CHUNKB(1, dB, dA);
    CHUNKB(2, dA, dB);
    CHUNKB(3, dB, dA);
    CHUNKB(4, dA, dB);
    CHUNKB(5, dB, dA);
    CHUNKB(6, dA, dB);
    CHUNKB(7, dB, dA);

#undef LOADC
#undef CHUNKB
}

extern "C" void kernel_launch(void* const* d_in, const int* in_sizes, int n_in,
                              void* d_out, int out_size, void* d_ws, size_t ws_size,
                              hipStream_t stream) {
    const float* x     = (const float*)d_in[0];
    const float* m     = (const float*)d_in[1];
    const float* var   = (const float*)d_in[2];
    const float* m_p   = (const float*)d_in[3];
    const float* var_p = (const float*)d_in[4];
    float* out = (float*)d_out;

    cn_pipe<<<NC, 1024, 0, stream>>>(x, m, var, m_p, var_p, out);
}

// Round 11
// 44.595 us; speedup vs baseline: 1.4739x; 1.0254x over previous
//
#include <hip/hip_runtime.h>

#define NB 32
#define NC 256
#define HW 4096
#define AFWD 0.999f
#define EPS 1e-5f
#define CH 4                 // planes per chunk
#define NCHUNK (NB / CH)     // 8 chunks

typedef float f32x4 __attribute__((ext_vector_type(4)));

// One block per channel, 1024 threads = 16 waves; chunk = 4 planes, 4 waves
// per plane. Single read of x. EMA via scalar recurrence, run REDUNDANTLY by
// every wave (lane-uniform, register state) -> no wave-0 bottleneck and only
// ONE barrier per chunk (sp[] double-buffered by chunk parity).
//
// Recurrence: tmp_i = sum_j a^(31-j) seq[i+j]  (seq = [m_p[1:], mu])
//   tmp_0    = D + mu_0,           D = sum_{j<31} a^(31-j) m_p[j+1]
//   tmp_i    = a*tmp_{i-1} - a^32 * m_p[i] + mu_i          (i >= 1)
//   mu_new_i = a^32 * m[i] + (1-a)*tmp_i ;  stale_i = i ? mu_new_{i-1} : m[31]
// (identical chain for var with vc_i = v_i + a*(mu_i - stale_i)^2)
__global__ __launch_bounds__(1024) void cn_pipe(
    const float* __restrict__ x,
    const float* __restrict__ m,
    const float* __restrict__ var,
    const float* __restrict__ m_p,
    const float* __restrict__ var_p,
    float* __restrict__ out)
{
    const int c = blockIdx.x;          // channel
    const int t = threadIdx.x;
    const int w = t >> 6, l = t & 63;
    const int p = w >> 2;              // plane-in-chunk 0..3
    const int q = w & 3;               // quarter 0..3

    __shared__ float m_s[NB], var_s[NB], mp_s[NB], vp_s[NB];
    __shared__ float sp[2][CH][4][2];  // [parity][plane][quarter][s,ss]

    // ---- prologue: small params to LDS (visible after chunk-0 barrier) ----
    if (t < NB) { m_s[t] = m[t * NC + c]; var_s[t] = var[t * NC + c]; }
    if (t >= 1 && t < NB) {
        mp_s[t] = m_p[t * NC + c];
        vp_s[t] = var_p[t * NC + c];
    }

    // per-wave initial window dots D, D2 (all lanes get the sum via butterfly)
    float D = 0.f, D2 = 0.f;
    if (l < NB - 1) {
        float pw = 1.f;
        for (int k = l; k < NB - 1; ++k) pw *= AFWD;   // a^(31-l)
        D  = pw * m_p[(l + 1) * NC + c];
        D2 = pw * var_p[(l + 1) * NC + c];
    }
#pragma unroll
    for (int o = 1; o < 64; o <<= 1) {
        D  += __shfl_xor(D, o, 64);
        D2 += __shfl_xor(D2, o, 64);
    }

    float a32 = 1.f;
#pragma unroll
    for (int k = 0; k < NB; ++k) a32 *= AFWD;          // constant-folds
    const float one_m = 1.f - AFWD;

    float tmp = 0.f, tmp2 = 0.f, prev_munew = 0.f, prev_varnew = 0.f;
    f32x4 dA[4], dB[4];

#define LOADC(DST, K) do {                                                    \
        const int b_ = (K) * CH + p;                                          \
        const f32x4* xp_ = (const f32x4*)(x + ((size_t)b_ * NC + c) * HW);    \
        _Pragma("unroll")                                                     \
        for (int i_ = 0; i_ < 4; ++i_) DST[i_] = xp_[q * 256 + i_ * 64 + l];  \
    } while (0)

#define CHUNKB(K, CUR, NXT) do {                                              \
        if ((K) + 1 < NCHUNK) LOADC(NXT, (K) + 1);   /* prefetch next */      \
        float s_ = 0.f, ss_ = 0.f;                                            \
        _Pragma("unroll")                                                     \
        for (int i_ = 0; i_ < 4; ++i_) {                                      \
            f32x4 a_ = CUR[i_];                                               \
            s_  += a_.x + a_.y + a_.z + a_.w;                                 \
            ss_ += a_.x * a_.x + a_.y * a_.y + a_.z * a_.z + a_.w * a_.w;     \
        }                                                                     \
        _Pragma("unroll")                                                     \
        for (int o_ = 32; o_ > 0; o_ >>= 1) {                                 \
            s_  += __shfl_down(s_, o_, 64);                                   \
            ss_ += __shfl_down(ss_, o_, 64);                                  \
        }                                                                     \
        if (l == 0) { sp[(K) & 1][p][q][0] = s_; sp[(K) & 1][p][q][1] = ss_; }\
        __syncthreads();                                                      \
        float muP = 0.f, rsP = 1.f;                                           \
        _Pragma("unroll")                                                     \
        for (int ii = 0; ii < CH; ++ii) {                                     \
            const int i = (K) * CH + ii;                                      \
            float S_  = sp[(K) & 1][ii][0][0] + sp[(K) & 1][ii][1][0]         \
                      + sp[(K) & 1][ii][2][0] + sp[(K) & 1][ii][3][0];        \
            float SS_ = sp[(K) & 1][ii][0][1] + sp[(K) & 1][ii][1][1]         \
                      + sp[(K) & 1][ii][2][1] + sp[(K) & 1][ii][3][1];        \
            float mu_i = S_ * (1.f / HW);                                     \
            float v_i  = SS_ * (1.f / HW) - mu_i * mu_i;                      \
            if (i == 0) tmp = D + mu_i;                                       \
            else        tmp = AFWD * tmp - a32 * mp_s[i] + mu_i;              \
            float munew = a32 * m_s[i] + one_m * tmp;                         \
            float must  = (i == 0) ? m_s[NB - 1] : prev_munew;                \
            float d_ = mu_i - must;                                           \
            float vc = v_i + AFWD * d_ * d_;                                  \
            if (i == 0) tmp2 = D2 + vc;                                       \
            else        tmp2 = AFWD * tmp2 - a32 * vp_s[i] + vc;              \
            float varnew = a32 * var_s[i] + one_m * tmp2;                     \
            float varst  = (i == 0) ? var_s[NB - 1] : prev_varnew;            \
            prev_munew = munew; prev_varnew = varnew;                         \
            if (ii == p) { muP = must; rsP = 1.f / sqrtf(varst + EPS); }      \
        }                                                                     \
        {                                                                     \
            const int b_ = (K) * CH + p;                                      \
            f32x4* op_ = (f32x4*)(out + ((size_t)b_ * NC + c) * HW);          \
            _Pragma("unroll")                                                 \
            for (int i_ = 0; i_ < 4; ++i_)                                    \
                __builtin_nontemporal_store((CUR[i_] - muP) * rsP,            \
                                            &op_[q * 256 + i_ * 64 + l]);     \
        }                                                                     \
    } while (0)

    LOADC(dA, 0);
    CHUNKB(0, dA, dB);
    CHUNKB(1, dB, dA);
    CHUNKB(2, dA, dB);
    CHUNKB(3, dB, dA);
    CHUNKB(4, dA, dB);
    CHUNKB(5, dB, dA);
    CHUNKB(6, dA, dB);
    CHUNKB(7, dB, dA);

#undef LOADC
#undef CHUNKB
}

extern "C" void kernel_launch(void* const* d_in, const int* in_sizes, int n_in,
                              void* d_out, int out_size, void* d_ws, size_t ws_size,
                              hipStream_t stream) {
    const float* x     = (const float*)d_in[0];
    const float* m     = (const float*)d_in[1];
    const float* var   = (const float*)d_in[2];
    const float* m_p   = (const float*)d_in[3];
    const float* var_p = (const float*)d_in[4];
    float* out = (float*)d_out;

    cn_pipe<<<NC, 1024, 0, stream>>>(x, m, var, m_p, var_p, out);
}